// Round 14
// baseline (71.005 us; speedup 1.0000x reference)
//
#include <hip/hip_runtime.h>

// VectorQuantizer on MI355X (gfx950) — single-pass fp16 MFMA scan + exact rescore.
// Round 13: geometry-only change (per-thread code identical -> bit-identical
// outputs). 1024-thread blocks x 256 blocks: 16 waves/block, ~70KB LDS ->
// 2 blocks/CU -> 32 waves/CU = 8 waves/SIMD (2x round-12 TLP; VGPR=64 makes
// this legal), and 256 blocks on 256 CUs = ONE dispatch round (staging
// amortized 2x, no second-prologue, no inter-round tail).

#define C_DIM   64
#define N_EMB   512
#define HW      4096
#define N_PIX   (32 * HW)            // 131072
#define ZQ_OFF  1
#define IDX_OFF (1 + N_PIX * C_DIM)
#define NBLK    256                  // 512 px per block, 2 blocks/CU, 1 round
#define TPB     1024

typedef _Float16 half8 __attribute__((ext_vector_type(8)));
typedef float    f32x4 __attribute__((ext_vector_type(4)));
union FragH { unsigned u[4]; half8 h8; uint4 u4; _Float16 h[8]; };

__device__ __forceinline__ unsigned umn(unsigned a, unsigned b){ return a<b?a:b; }
__device__ __forceinline__ unsigned umx(unsigned a, unsigned b){ return a>b?a:b; }

__global__ __launch_bounds__(TPB, 8) void vq_main(
    const float* __restrict__ z,
    const float* __restrict__ cb,
    float* __restrict__ out,
    float* __restrict__ ws)
{
    __shared__ unsigned cbh[N_EMB * 32];   // 64KB codebook as fp16 pairs (e*512), swizzled
    __shared__ float    esh5[N_EMB];       // esum + 0.5 (scan keys, positive d)
    __shared__ float    eshx[N_EMB];       // numpy-exact esum (rescore)
    __shared__ float    wsum[16];

    const int t = threadIdx.x;             // 0..1023

    // ---- Stage codebook (threads 0..511: thread t owns code row t) ----
    if (t < N_EMB) {
        const float* e = cb + t * C_DIM;
        float ev[64];
        #pragma unroll
        for (int q = 0; q < 16; ++q) {
            float4 v = ((const float4*)e)[q];
            ev[4*q+0]=v.x; ev[4*q+1]=v.y; ev[4*q+2]=v.z; ev[4*q+3]=v.w;
        }
        // numpy pairwise_sum(n=64): 8 accs, rounded mul, tree combine
        float r[8];
        #pragma unroll
        for (int i = 0; i < 8; ++i) r[i] = __fmul_rn(ev[i], ev[i]);
        #pragma unroll
        for (int k = 8; k < 64; k += 8) {
            #pragma unroll
            for (int i = 0; i < 8; ++i)
                r[i] = __fadd_rn(r[i], __fmul_rn(ev[k+i], ev[k+i]));
        }
        float es = __fadd_rn(
            __fadd_rn(__fadd_rn(r[0],r[1]), __fadd_rn(r[2],r[3])),
            __fadd_rn(__fadd_rn(r[4],r[5]), __fadd_rn(r[6],r[7])));
        eshx[t] = es;
        esh5[t] = es + 0.5f;
        unsigned hw_[32];
        #pragma unroll
        for (int w2 = 0; w2 < 32; ++w2) {
            union { _Float16 h[2]; unsigned u; } pk;
            pk.h[0] = (_Float16)(ev[2*w2]   * 512.0f);
            pk.h[1] = (_Float16)(ev[2*w2+1] * 512.0f);
            hw_[w2] = pk.u;
        }
        const int rs = t & 7;
        #pragma unroll
        for (int g = 0; g < 8; ++g) {
            int g2 = g ^ rs;
            *(uint4*)&cbh[t*32 + g2*4] =
                make_uint4(hw_[4*g], hw_[4*g+1], hw_[4*g+2], hw_[4*g+3]);
        }
    }
    __syncthreads();

    const int l   = t & 63;
    const int wv  = t >> 6;                // wave 0..15
    const int lg  = l >> 4;                // k-chunk / candidate group 0..3
    const int li  = l & 15;                // pixel col / code row in tile
    const int bb  = blockIdx.x >> 3;       // batch (512 px per block, 4096 per b)
    const int g20 = (lg)     ^ (li & 7);   // swizzled granule, k-step 0
    const int g21 = (4 + lg) ^ (li & 7);   // swizzled granule, k-step 1
    const int jb  = lg * 4;
    float ls = 0.f;

    // ---- B-fragments for both pixel-tiles (wave covers 32 consecutive px) ----
    const int pxw0 = blockIdx.x * 512 + wv * 32;     // wave px base
    const float* zb0 = z + (size_t)bb * (C_DIM * HW) + ((pxw0      + li) & (HW-1));
    const float* zb1 = z + (size_t)bb * (C_DIM * HW) + ((pxw0 + 16 + li) & (HW-1));
    FragH bA0, bA1, bB0, bB1;
    {
        const float* c0 = zb0 + (size_t)(lg*8) * HW;
        const float* c1 = zb0 + (size_t)(32 + lg*8) * HW;
        const float* c2 = zb1 + (size_t)(lg*8) * HW;
        const float* c3 = zb1 + (size_t)(32 + lg*8) * HW;
        #pragma unroll
        for (int i = 0; i < 8; ++i) {
            bA0.h[i] = (_Float16)c0[(size_t)i*HW];
            bA1.h[i] = (_Float16)c1[(size_t)i*HW];
            bB0.h[i] = (_Float16)c2[(size_t)i*HW];
            bB1.h[i] = (_Float16)c3[(size_t)i*HW];
        }
    }

    // ---- MFMA scan: 32 code-tiles; per-lane top-3 keys per pixel-tile ----
    unsigned k1A=0xFFFFFFFFu,k2A=0xFFFFFFFFu,k3A=0xFFFFFFFFu;
    unsigned k1B=0xFFFFFFFFu,k2B=0xFFFFFFFFu,k3B=0xFFFFFFFFu;
    #pragma unroll 4
    for (int T = 0; T < 32; ++T) {
        const int row = T*16 + li;
        FragH a0, a1;
        a0.u4 = *(const uint4*)&cbh[row*32 + g20*4];
        a1.u4 = *(const uint4*)&cbh[row*32 + g21*4];
        f32x4 es = *(const f32x4*)&esh5[T*16 + jb];
        f32x4 accA = {0.f,0.f,0.f,0.f}, accB = {0.f,0.f,0.f,0.f};
        accA = __builtin_amdgcn_mfma_f32_16x16x32_f16(a0.h8, bA0.h8, accA, 0,0,0);
        accA = __builtin_amdgcn_mfma_f32_16x16x32_f16(a1.h8, bA1.h8, accA, 0,0,0);
        accB = __builtin_amdgcn_mfma_f32_16x16x32_f16(a0.h8, bB0.h8, accB, 0,0,0);
        accB = __builtin_amdgcn_mfma_f32_16x16x32_f16(a1.h8, bB1.h8, accB, 0,0,0);
        const int jT = T*16 + jb;
        #pragma unroll
        for (int r2 = 0; r2 < 4; ++r2) {
            float dA = __fmaf_rn(-0.00390625f, accA[r2], es[r2]);  // >0 -> uint-sortable
            float dB = __fmaf_rn(-0.00390625f, accB[r2], es[r2]);
            unsigned keyA = (__float_as_uint(dA) & 0xFFFFFE00u) | (unsigned)(jT + r2);
            unsigned keyB = (__float_as_uint(dB) & 0xFFFFFE00u) | (unsigned)(jT + r2);
            unsigned m1,M1,m2,M2;
            m1=umn(k1A,keyA); M1=umx(k1A,keyA); k1A=m1;
            m2=umn(k2A,M1);   M2=umx(k2A,M1);   k2A=m2; k3A=umn(k3A,M2);
            m1=umn(k1B,keyB); M1=umx(k1B,keyB); k1B=m1;
            m2=umn(k2B,M1);   M2=umx(k2B,M1);   k2B=m2; k3B=umn(k3B,M2);
        }
    }

    // ---- unified rescore: lanes lg0,lg1 own pt0's pixel li; lg2,lg3 own pt1's.
    unsigned f1 = __shfl_xor(k1A, 32, 64), f2 = __shfl_xor(k2A, 32, 64), f3 = __shfl_xor(k3A, 32, 64);
    unsigned h1 = __shfl_xor(k1B, 32, 64), h2 = __shfl_xor(k2B, 32, 64), h3 = __shfl_xor(k3B, 32, 64);
    const bool isB = (l >= 32);
    unsigned c0 = isB ? k1B : k1A, c1 = isB ? k2B : k2A, c2 = isB ? k3B : k3A;
    unsigned c3 = isB ? h1  : f1,  c4 = isB ? h2  : f2,  c5 = isB ? h3  : f3;

    const float* zb = isB ? zb1 : zb0;
    const int px = pxw0 + (isB ? 16 : 0) + li;

    // zr reload: 32 consecutive px across the wave per c-plane (full 128B lines)
    float zr[64];
    #pragma unroll
    for (int c = 0; c < 64; ++c) zr[c] = zb[(size_t)c * HW];
    float ap;
    {   // numpy-exact ||z||^2
        float r[8];
        #pragma unroll
        for (int i = 0; i < 8; ++i) r[i] = __fmul_rn(zr[i], zr[i]);
        #pragma unroll
        for (int k = 8; k < 64; k += 8) {
            #pragma unroll
            for (int i = 0; i < 8; ++i)
                r[i] = __fadd_rn(r[i], __fmul_rn(zr[k+i], zr[k+i]));
        }
        ap = __fadd_rn(
            __fadd_rn(__fadd_rn(r[0],r[1]), __fadd_rn(r[2],r[3])),
            __fadd_rn(__fadd_rn(r[4],r[5]), __fadd_rn(r[6],r[7])));
    }

    // pixel-global kmin over 12 candidates: local 6 + pair partner (xor 16)
    unsigned kmin = umn(umn(c0, c1), umn(umn(c2, c3), umn(c4, c5)));
    kmin = umn(kmin, __shfl_xor(kmin, 16, 64));
    const float thr = __uint_as_float(kmin & 0xFFFFFE00u) + 1.2e-4f;
    float bd = 3.0e38f; int bj = 1023;

    #define RESCORE(K) do {                                               \
        float da_ = __uint_as_float((K) & 0xFFFFFE00u);                   \
        if (da_ <= thr) {                                                 \
            int j_ = (int)((K) & 511u);                                   \
            const float* er_ = cb + (size_t)j_ * 64;                      \
            float a_ = 0.f;                                               \
            _Pragma("unroll")                                             \
            for (int c_ = 0; c_ < 64; ++c_)                               \
                a_ = __fmaf_rn(zr[c_], er_[c_], a_);                      \
            float dd_ = __fsub_rn(__fadd_rn(ap, eshx[j_]),                \
                                  __fmul_rn(2.0f, a_));                   \
            if (dd_ < bd || (dd_ == bd && j_ < bj)) { bd = dd_; bj = j_; }\
        }                                                                 \
    } while (0)
    RESCORE(c0); RESCORE(c1); RESCORE(c2);
    RESCORE(c3); RESCORE(c4); RESCORE(c5);
    #undef RESCORE

    // lexicographic (d, j) pair-merge == np.argmin first-min
    {
        float od = __shfl_xor(bd, 16, 64);
        int   oj = __shfl_xor(bj, 16, 64);
        if (od < bd || (od == bd && oj < bj)) { bd = od; bj = oj; }
    }
    if ((l & 16) == 0) {                   // lg0 writes pt0, lg2 writes pt1
        out[IDX_OFF + px] = (float)bj;
        ls += bd;                          // exact ||z - e_bj||^2 (incl. ap)
    }

    // ---- z_q write: both tiles together -> full 128B lines ----
    {
        const int pm  = l & 31;
        const int hh  = l >> 5;
        const int src = (pm & 15) | ((pm & 16) << 1);   // owner lane of px pm
        const int bjw = __shfl(bj, src, 64);
        const float* eb = cb + (size_t)bjw * 64;
        float* zq = out + ZQ_OFF + (size_t)bb * (C_DIM * HW) + ((pxw0 + pm) & (HW-1));
        #pragma unroll
        for (int cc = 0; cc < 32; ++cc) {
            int c = hh * 32 + cc;
            zq[(size_t)c * HW] = eb[c];    // 32 px x 2 planes = 2 full lines/instr
        }
    }

    // ---- loss reduce: wave -> block -> ws ----
    #pragma unroll
    for (int off = 32; off; off >>= 1) ls += __shfl_down(ls, off, 64);
    if (l == 0) wsum[wv] = ls;
    __syncthreads();
    if (t == 0) {
        float s = 0.f;
        #pragma unroll
        for (int i = 0; i < 16; ++i) s += wsum[i];
        ws[blockIdx.x] = s;
    }
}

__global__ __launch_bounds__(256) void vq_loss(
    const float* __restrict__ ws, float* __restrict__ out)
{
    __shared__ float sm[4];
    float v = ws[threadIdx.x];              // 256 block partials
    #pragma unroll
    for (int off = 32; off; off >>= 1) v += __shfl_down(v, off, 64);
    const int lane = threadIdx.x & 63, wid = threadIdx.x >> 6;
    if (lane == 0) sm[wid] = v;
    __syncthreads();
    if (threadIdx.x == 0)
        out[0] = ((sm[0] + sm[1]) + (sm[2] + sm[3])) * (1.0f / 8388608.0f);
}

extern "C" void kernel_launch(void* const* d_in, const int* in_sizes, int n_in,
                              void* d_out, int out_size, void* d_ws, size_t ws_size,
                              hipStream_t stream)
{
    const float* z  = (const float*)d_in[0];   // 8388608 f32
    const float* cb = (const float*)d_in[1];   // 32768 f32
    float* out = (float*)d_out;
    float* ws  = (float*)d_ws;                 // 256 f32 partials

    vq_main<<<NBLK, TPB, 0, stream>>>(z, cb, out, ws);
    vq_loss<<<1, 256, 0, stream>>>(ws, out);
}

// Round 15
// 47.712 us; speedup vs baseline: 1.4882x; 1.4882x over previous
//
#include <hip/hip_runtime.h>

// VectorQuantizer on MI355X (gfx950) — fp16 MFMA scan + exact numpy rescore.
// Round 14: remove the LDS dependence entirely. A prep kernel writes the scan
// tables to d_ws once (fp16(e*512) in wave-coalesced tiles + esum arrays,
// numerically identical to the old per-block staging -> bit-identical output).
// Main kernel: no staging prologue, no barriers in the scan, ~0 LDS ->
// 256-thread blocks pack 8/CU at VGPR=64 -> 8 waves/SIMD (2x round 12), which
// is what the key-insert dependency-chain stall needs. launch_bounds(256,4)
// keeps the VGPR cap at 128 (round 13's forced cap=32 disaster avoided);
// allocator has chosen 64 naturally for 3 rounds.

#define C_DIM   64
#define N_EMB   512
#define HW      4096
#define N_PIX   (32 * HW)            // 131072
#define ZQ_OFF  1
#define IDX_OFF (1 + N_PIX * C_DIM)
#define NBLK    1024                 // 128 px per block, 256 thr, ~0 LDS
// d_ws layout (floats): [0..16384) cb16 tiles (64KB as u32), 
// [16384..16896) esh5, [16896..17408) eshx, [17408..18432) loss partials
#define WS_ESH5 16384
#define WS_ESHX 16896
#define WS_LOSS 17408

typedef _Float16 half8 __attribute__((ext_vector_type(8)));
typedef float    f32x4 __attribute__((ext_vector_type(4)));
union FragH { unsigned u[4]; half8 h8; uint4 u4; _Float16 h[8]; };

__device__ __forceinline__ unsigned umn(unsigned a, unsigned b){ return a<b?a:b; }
__device__ __forceinline__ unsigned umx(unsigned a, unsigned b){ return a>b?a:b; }

// ---- prep: thread = code j. fp16(e*512) into tiled layout + esum arrays ----
__global__ __launch_bounds__(64) void vq_prep(
    const float* __restrict__ cb, float* __restrict__ wsf)
{
    const int j = blockIdx.x * 64 + threadIdx.x;      // 0..511
    const float* e = cb + j * C_DIM;
    float ev[64];
    #pragma unroll
    for (int q = 0; q < 16; ++q) {
        float4 v = ((const float4*)e)[q];
        ev[4*q+0]=v.x; ev[4*q+1]=v.y; ev[4*q+2]=v.z; ev[4*q+3]=v.w;
    }
    // numpy pairwise_sum(n=64): 8 accs, rounded mul, tree combine
    float r[8];
    #pragma unroll
    for (int i = 0; i < 8; ++i) r[i] = __fmul_rn(ev[i], ev[i]);
    #pragma unroll
    for (int k = 8; k < 64; k += 8) {
        #pragma unroll
        for (int i = 0; i < 8; ++i)
            r[i] = __fadd_rn(r[i], __fmul_rn(ev[k+i], ev[k+i]));
    }
    float es = __fadd_rn(
        __fadd_rn(__fadd_rn(r[0],r[1]), __fadd_rn(r[2],r[3])),
        __fadd_rn(__fadd_rn(r[4],r[5]), __fadd_rn(r[6],r[7])));
    wsf[WS_ESHX + j] = es;
    wsf[WS_ESH5 + j] = es + 0.5f;
    // pack fp16(e*512) pairs; tiled layout: granule g=(s*4+lg) of code j=T*16+li
    // lives at uint4 index (T*8+g)*16+li  -> a wave's kstep read is 4 groups of
    // 16 contiguous 16B lanes (fully coalesced).
    unsigned hw_[32];
    #pragma unroll
    for (int w2 = 0; w2 < 32; ++w2) {
        union { _Float16 h[2]; unsigned u; } pk;
        pk.h[0] = (_Float16)(ev[2*w2]   * 512.0f);
        pk.h[1] = (_Float16)(ev[2*w2+1] * 512.0f);
        hw_[w2] = pk.u;
    }
    const int T = j >> 4, li = j & 15;
    uint4* dst = (uint4*)wsf;
    #pragma unroll
    for (int g = 0; g < 8; ++g)
        dst[(T*8 + g)*16 + li] =
            make_uint4(hw_[4*g], hw_[4*g+1], hw_[4*g+2], hw_[4*g+3]);
}

__global__ __launch_bounds__(256, 4) void vq_main(
    const float* __restrict__ z,
    const float* __restrict__ cb,
    float* __restrict__ out,
    float* __restrict__ wsf)
{
    __shared__ float wsum[4];

    const int t   = threadIdx.x;           // 0..255
    const int l   = t & 63;
    const int wv  = t >> 6;                // wave 0..3
    const int lg  = l >> 4;                // k-chunk / candidate group 0..3
    const int li  = l & 15;                // pixel col / code row in tile
    const int bb  = blockIdx.x >> 5;       // batch (128 px per block, 4096 per b)
    float ls = 0.f;

    const uint4* __restrict__ cbt  = (const uint4*)wsf;
    const float* __restrict__ esh5 = wsf + WS_ESH5;
    const float* __restrict__ eshx = wsf + WS_ESHX;

    // ---- B-fragments for both pixel-tiles (wave covers 32 consecutive px) ----
    const int pxw0 = blockIdx.x * 128 + wv * 32;     // wave px base
    const float* zb0 = z + (size_t)bb * (C_DIM * HW) + ((pxw0      + li) & (HW-1));
    const float* zb1 = z + (size_t)bb * (C_DIM * HW) + ((pxw0 + 16 + li) & (HW-1));
    FragH bA0, bA1, bB0, bB1;
    {
        const float* c0 = zb0 + (size_t)(lg*8) * HW;
        const float* c1 = zb0 + (size_t)(32 + lg*8) * HW;
        const float* c2 = zb1 + (size_t)(lg*8) * HW;
        const float* c3 = zb1 + (size_t)(32 + lg*8) * HW;
        #pragma unroll
        for (int i = 0; i < 8; ++i) {
            bA0.h[i] = (_Float16)c0[(size_t)i*HW];
            bA1.h[i] = (_Float16)c1[(size_t)i*HW];
            bB0.h[i] = (_Float16)c2[(size_t)i*HW];
            bB1.h[i] = (_Float16)c3[(size_t)i*HW];
        }
    }

    // ---- MFMA scan: 32 code-tiles; A-frags + esum from global (L2-hot) ----
    unsigned k1A=0xFFFFFFFFu,k2A=0xFFFFFFFFu,k3A=0xFFFFFFFFu;
    unsigned k1B=0xFFFFFFFFu,k2B=0xFFFFFFFFu,k3B=0xFFFFFFFFu;
    const int jb = lg * 4;
    #pragma unroll 4
    for (int T = 0; T < 32; ++T) {
        FragH a0, a1;
        a0.u4 = cbt[(T*8 +     lg)*16 + li];   // kstep 0, coalesced 16-lane runs
        a1.u4 = cbt[(T*8 + 4 + lg)*16 + li];   // kstep 1
        f32x4 es = *(const f32x4*)&esh5[T*16 + jb];
        f32x4 accA = {0.f,0.f,0.f,0.f}, accB = {0.f,0.f,0.f,0.f};
        accA = __builtin_amdgcn_mfma_f32_16x16x32_f16(a0.h8, bA0.h8, accA, 0,0,0);
        accA = __builtin_amdgcn_mfma_f32_16x16x32_f16(a1.h8, bA1.h8, accA, 0,0,0);
        accB = __builtin_amdgcn_mfma_f32_16x16x32_f16(a0.h8, bB0.h8, accB, 0,0,0);
        accB = __builtin_amdgcn_mfma_f32_16x16x32_f16(a1.h8, bB1.h8, accB, 0,0,0);
        const int jT = T*16 + jb;
        #pragma unroll
        for (int r2 = 0; r2 < 4; ++r2) {
            float dA = __fmaf_rn(-0.00390625f, accA[r2], es[r2]);  // >0 -> uint-sortable
            float dB = __fmaf_rn(-0.00390625f, accB[r2], es[r2]);
            unsigned keyA = (__float_as_uint(dA) & 0xFFFFFE00u) | (unsigned)(jT + r2);
            unsigned keyB = (__float_as_uint(dB) & 0xFFFFFE00u) | (unsigned)(jT + r2);
            unsigned m1,M1,m2,M2;
            m1=umn(k1A,keyA); M1=umx(k1A,keyA); k1A=m1;
            m2=umn(k2A,M1);   M2=umx(k2A,M1);   k2A=m2; k3A=umn(k3A,M2);
            m1=umn(k1B,keyB); M1=umx(k1B,keyB); k1B=m1;
            m2=umn(k2B,M1);   M2=umx(k2B,M1);   k2B=m2; k3B=umn(k3B,M2);
        }
    }

    // ---- unified rescore: lanes lg0,lg1 own pt0's pixel li; lg2,lg3 own pt1's.
    unsigned f1 = __shfl_xor(k1A, 32, 64), f2 = __shfl_xor(k2A, 32, 64), f3 = __shfl_xor(k3A, 32, 64);
    unsigned h1 = __shfl_xor(k1B, 32, 64), h2 = __shfl_xor(k2B, 32, 64), h3 = __shfl_xor(k3B, 32, 64);
    const bool isB = (l >= 32);
    unsigned c0 = isB ? k1B : k1A, c1 = isB ? k2B : k2A, c2 = isB ? k3B : k3A;
    unsigned c3 = isB ? h1  : f1,  c4 = isB ? h2  : f2,  c5 = isB ? h3  : f3;

    const float* zb = isB ? zb1 : zb0;
    const int px = pxw0 + (isB ? 16 : 0) + li;

    // zr reload: 32 consecutive px across the wave per c-plane (full 128B lines)
    float zr[64];
    #pragma unroll
    for (int c = 0; c < 64; ++c) zr[c] = zb[(size_t)c * HW];
    float ap;
    {   // numpy-exact ||z||^2
        float r[8];
        #pragma unroll
        for (int i = 0; i < 8; ++i) r[i] = __fmul_rn(zr[i], zr[i]);
        #pragma unroll
        for (int k = 8; k < 64; k += 8) {
            #pragma unroll
            for (int i = 0; i < 8; ++i)
                r[i] = __fadd_rn(r[i], __fmul_rn(zr[k+i], zr[k+i]));
        }
        ap = __fadd_rn(
            __fadd_rn(__fadd_rn(r[0],r[1]), __fadd_rn(r[2],r[3])),
            __fadd_rn(__fadd_rn(r[4],r[5]), __fadd_rn(r[6],r[7])));
    }

    // pixel-global kmin over 12 candidates: local 6 + pair partner (xor 16)
    unsigned kmin = umn(umn(c0, c1), umn(umn(c2, c3), umn(c4, c5)));
    kmin = umn(kmin, __shfl_xor(kmin, 16, 64));
    const float thr = __uint_as_float(kmin & 0xFFFFFE00u) + 1.2e-4f;
    float bd = 3.0e38f; int bj = 1023;

    #define RESCORE(K) do {                                               \
        float da_ = __uint_as_float((K) & 0xFFFFFE00u);                   \
        if (da_ <= thr) {                                                 \
            int j_ = (int)((K) & 511u);                                   \
            const float* er_ = cb + (size_t)j_ * 64;                      \
            float a_ = 0.f;                                               \
            _Pragma("unroll")                                             \
            for (int c_ = 0; c_ < 64; ++c_)                               \
                a_ = __fmaf_rn(zr[c_], er_[c_], a_);                      \
            float dd_ = __fsub_rn(__fadd_rn(ap, eshx[j_]),                \
                                  __fmul_rn(2.0f, a_));                   \
            if (dd_ < bd || (dd_ == bd && j_ < bj)) { bd = dd_; bj = j_; }\
        }                                                                 \
    } while (0)
    RESCORE(c0); RESCORE(c1); RESCORE(c2);
    RESCORE(c3); RESCORE(c4); RESCORE(c5);
    #undef RESCORE

    // lexicographic (d, j) pair-merge == np.argmin first-min
    {
        float od = __shfl_xor(bd, 16, 64);
        int   oj = __shfl_xor(bj, 16, 64);
        if (od < bd || (od == bd && oj < bj)) { bd = od; bj = oj; }
    }
    if ((l & 16) == 0) {                   // lg0 writes pt0, lg2 writes pt1
        out[IDX_OFF + px] = (float)bj;
        ls += bd;                          // exact ||z - e_bj||^2 (incl. ap)
    }

    // ---- z_q write: both tiles together -> full 128B lines ----
    {
        const int pm  = l & 31;
        const int hh  = l >> 5;
        const int src = (pm & 15) | ((pm & 16) << 1);   // owner lane of px pm
        const int bjw = __shfl(bj, src, 64);
        const float* eb = cb + (size_t)bjw * 64;
        float* zq = out + ZQ_OFF + (size_t)bb * (C_DIM * HW) + ((pxw0 + pm) & (HW-1));
        #pragma unroll
        for (int cc = 0; cc < 32; ++cc) {
            int c = hh * 32 + cc;
            zq[(size_t)c * HW] = eb[c];    // 32 px x 2 planes = 2 full lines/instr
        }
    }

    // ---- loss reduce: wave -> block -> ws ----
    #pragma unroll
    for (int off = 32; off; off >>= 1) ls += __shfl_down(ls, off, 64);
    if (l == 0) wsum[wv] = ls;
    __syncthreads();
    if (t == 0)
        wsf[WS_LOSS + blockIdx.x] = (wsum[0] + wsum[1]) + (wsum[2] + wsum[3]);
}

__global__ __launch_bounds__(256) void vq_loss(
    const float* __restrict__ wsf, float* __restrict__ out)
{
    __shared__ float sm[4];
    const float* p = wsf + WS_LOSS;        // 1024 block partials
    float v = (p[threadIdx.x]       + p[threadIdx.x + 256])
            + (p[threadIdx.x + 512] + p[threadIdx.x + 768]);
    #pragma unroll
    for (int off = 32; off; off >>= 1) v += __shfl_down(v, off, 64);
    const int lane = threadIdx.x & 63, wid = threadIdx.x >> 6;
    if (lane == 0) sm[wid] = v;
    __syncthreads();
    if (threadIdx.x == 0)
        out[0] = ((sm[0] + sm[1]) + (sm[2] + sm[3])) * (1.0f / 8388608.0f);
}

extern "C" void kernel_launch(void* const* d_in, const int* in_sizes, int n_in,
                              void* d_out, int out_size, void* d_ws, size_t ws_size,
                              hipStream_t stream)
{
    const float* z  = (const float*)d_in[0];   // 8388608 f32
    const float* cb = (const float*)d_in[1];   // 32768 f32
    float* out = (float*)d_out;
    float* wsf = (float*)d_ws;                 // needs ~74KB scratch

    vq_prep<<<8, 64, 0, stream>>>(cb, wsf);
    vq_main<<<NBLK, 256, 0, stream>>>(z, cb, out, wsf);
    vq_loss<<<1, 256, 0, stream>>>(wsf, out);
}